// Round 9
// baseline (460.031 us; speedup 1.0000x reference)
//
#include <hip/hip_runtime.h>

#define N_NODES 100000
#define NE      1600000
#define C       128
#define NB      98        // buckets of 1024 destination nodes
#define BCAP    19968     // per-bucket sedge capacity; mean 16327, ~28-sigma margin
#define EPB     4096      // edges per binA block
#define NBLKA   391       // ceil(NE/EPB)

typedef __attribute__((ext_vector_type(8))) short short8;
typedef __attribute__((ext_vector_type(4))) float float4v;

__device__ __forceinline__ unsigned short bf16rne(float f) {
    unsigned int u = __float_as_uint(f);
    return (unsigned short)((u + 0x7FFFu + ((u >> 16) & 1u)) >> 16);
}
__device__ __forceinline__ float blo(unsigned int u) { return __uint_as_float(u << 16); }
__device__ __forceinline__ float bhi(unsigned int u) { return __uint_as_float(u & 0xFFFF0000u); }

// ---- binA: block-grouped bucket records, NO global atomics ----------------
// Each block stages its EPB edges grouped by bucket in LDS, then dumps them
// coalesced to its own babuf region [blk*EPB, blk*EPB+valid) and writes the
// per-(bucket,block) counts to hcntg[bin*NBLKA + blk] (plain stores).
// Last block (gridDim-1) does the W transpose (wt3) instead.
__global__ __launch_bounds__(256) void binA_kernel(const int* __restrict__ row,
                                                   const int* __restrict__ col,
                                                   const float* __restrict__ ew,
                                                   int* __restrict__ hcntg,
                                                   uint2* __restrict__ babuf,
                                                   const float* __restrict__ W1,
                                                   const float* __restrict__ W2,
                                                   const float* __restrict__ W3,
                                                   unsigned short* __restrict__ Wt) {
    if (blockIdx.x == NBLKA) {   // wt3: Wt[l][n][k] = bf16(Wl[k][n])
        for (int i = threadIdx.x; i < 3 * 16384; i += 256) {
            int layer = i >> 14, r = i & 16383;
            int n = r >> 7, k = r & 127;
            const float* W = layer == 0 ? W1 : (layer == 1 ? W2 : W3);
            Wt[i] = bf16rne(W[k * 128 + n]);
        }
        return;
    }
    __shared__ int   hcnt[NB];
    __shared__ int   hofs[NB];
    __shared__ int   lofs[NB];
    __shared__ int   scn[128];
    __shared__ uint2 recs[EPB];   // 32 KB
    const int t = threadIdx.x;
    for (int i = t; i < NB; i += 256) { hcnt[i] = 0; hofs[i] = 0; }
    __syncthreads();

    const int e0 = blockIdx.x * EPB;
    int cc[16], rr[16]; float ee[16];
#pragma unroll
    for (int i = 0; i < 16; i++) {
        int e = e0 + i * 256 + t;
        if (e < NE) { cc[i] = col[e]; rr[i] = row[e]; ee[i] = ew[e]; }
        else cc[i] = -1;
    }
#pragma unroll
    for (int i = 0; i < 16; i++)
        if (cc[i] >= 0) atomicAdd(&hcnt[cc[i] >> 10], 1);
    __syncthreads();
    // parallel exclusive scan of hcnt (Hillis-Steele over 128, 7 rounds)
    if (t < 128) scn[t] = (t < NB) ? hcnt[t] : 0;
    __syncthreads();
    for (int off = 1; off < 128; off <<= 1) {
        int v = 0;
        if (t < 128 && t >= off) v = scn[t - off];
        __syncthreads();
        if (t < 128) scn[t] += v;
        __syncthreads();
    }
    if (t < NB) lofs[t] = scn[t] - hcnt[t];
    __syncthreads();
#pragma unroll
    for (int i = 0; i < 16; i++) {
        if (cc[i] < 0) continue;
        int b = cc[i] >> 10;
        int lpos = atomicAdd(&hofs[b], 1);
        int si = lofs[b] + lpos;
        unsigned int meta = ((unsigned int)(cc[i] & 1023) << 17) | (unsigned int)rr[i];
        recs[si] = make_uint2(meta, __float_as_uint(ee[i]));
    }
    __syncthreads();
    const int valid = lofs[NB - 1] + hcnt[NB - 1];
    uint2* myreg = babuf + (size_t)blockIdx.x * EPB;
    for (int i = t; i < valid; i += 256) myreg[i] = recs[i];
    if (t < NB) hcntg[t * NBLKA + blockIdx.x] = hcnt[t];
}

// ---- binB: per-bucket assemble from 391 block-grouped slices --------------
// Slice offsets from hcntg column sums; records streamed by global index via
// LDS binary search; single-pass reg-staged histogram (packed u64) + scan +
// cursor2/dinv emit + register-sourced scatter (r8-proven structure).
__global__ __launch_bounds__(1024) void binB_kernel(const int* __restrict__ hcntg,
                                                    const uint2* __restrict__ babuf,
                                                    float* __restrict__ dinv,
                                                    uint2* __restrict__ cursor2,
                                                    uint2* __restrict__ sedge) {
    __shared__ unsigned long long pk[1024];   // 8 KB
    __shared__ int ofs[1024];
    __shared__ int wtot[16];
    __shared__ int P[NBLKA];      // inclusive prefix of per-slice counts
    __shared__ int sofs[NBLKA];   // offset of this bucket within slice k
    const int b = blockIdx.x, t = threadIdx.x;
    const int n0 = b << 10;
    const int nn = min(1024, N_NODES - n0);

    pk[t] = 0ull;
    for (int k = t; k < NBLKA; k += 1024) {
        int s = 0;
        for (int bb = 0; bb < b; bb++) s += hcntg[bb * NBLKA + k];
        sofs[k] = s;
        P[k] = hcntg[b * NBLKA + k];
    }
    __syncthreads();
    if (t == 0) {                 // serial inclusive scan over 391 (cheap)
        int run = 0;
        for (int k = 0; k < NBLKA; k++) { run += P[k]; P[k] = run; }
    }
    __syncthreads();
    const int total = P[NBLKA - 1];

    uint2 rec[20];
#pragma unroll
    for (int slot = 0; slot < 20; slot++) {
        int g = (slot << 10) + t;
        uint2 m = make_uint2(0u, 0u);
        if (g < total) {
            int lo = 0, hi = NBLKA - 1;
            while (lo < hi) { int mid = (lo + hi) >> 1; if (P[mid] <= g) lo = mid + 1; else hi = mid; }
            int base = lo ? P[lo - 1] : 0;
            m = babuf[(size_t)lo * EPB + sofs[lo] + (g - base)];
            unsigned long long add = (1ull << 44) +
                (unsigned long long)(__uint_as_float(m.y) * 4294967296.0f);
            atomicAdd(&pk[m.x >> 17], add);
        }
        rec[slot] = m;
    }
    __syncthreads();

    const unsigned long long p = pk[t];
    const int myc = (int)(p >> 44);
    const float deg = (float)(p & ((1ull << 44) - 1)) * (1.0f / 4294967296.0f);
    if (t < nn) dinv[n0 + t] = 1.0f / sqrtf(deg + 1.0f);

    // two-level inclusive scan of myc
    const int lane64 = t & 63, w = t >> 6;
    int s = myc;
#pragma unroll
    for (int off = 1; off < 64; off <<= 1) {
        int u = __shfl_up(s, off);
        if (lane64 >= off) s += u;
    }
    if (lane64 == 63) wtot[w] = s;
    __syncthreads();
    if (t < 16) {
        int u = wtot[t];
#pragma unroll
        for (int off = 1; off < 16; off <<= 1) {
            int uu = __shfl_up(u, off);
            if (t >= off) u += uu;
        }
        wtot[t] = u;
    }
    __syncthreads();
    const int excl = s + (w ? wtot[w - 1] : 0) - myc;
    ofs[t] = excl;

    const unsigned int ebase = (unsigned int)b * BCAP;
    if (t < nn) {
        unsigned int st = ebase + (unsigned int)excl;
        cursor2[n0 + t] = make_uint2(st, st + (unsigned int)myc);
    }
    __syncthreads();

#pragma unroll
    for (int slot = 0; slot < 20; slot++) {
        int g = (slot << 10) + t;
        if (g < total) {
            uint2 m = rec[slot];
            int cl = m.x >> 17;
            int pp = atomicAdd(&ofs[cl], 1);
            sedge[(size_t)b * BCAP + pp] = make_uint2(m.x & 0x1FFFFu, m.y);
        }
    }
}

// ------- MFMA GEMM (layer 1 only), T = bf16( dinv * (X @ W) ) --------------
__global__ __launch_bounds__(256) void gemm_mfma(const float* __restrict__ Xf,
                                                 const unsigned short* __restrict__ Wt,
                                                 const float* __restrict__ dinv,
                                                 unsigned short* __restrict__ Yb,
                                                 int n) {
    __shared__ unsigned short sW[128 * 136];   // [outcol][k], +8 pad
    const int tid = threadIdx.x;

    for (int i = tid; i < 128 * 16; i += 256) {
        int nr = i >> 4, q = i & 15;
        *(uint4*)&sW[nr * 136 + q * 8] = ((const uint4*)Wt)[i];
    }
    __syncthreads();

    const int wave = tid >> 6, lane = tid & 63;
    const int m = lane & 15, quad = lane >> 4;
    const int node0 = blockIdx.x * 128 + wave * 32;
    const int nodeA = node0 + m;
    const int nodeB = node0 + 16 + m;

    float4v acc[2][8];
#pragma unroll
    for (int nt = 0; nt < 2; nt++)
#pragma unroll
        for (int t = 0; t < 8; t++) acc[nt][t] = (float4v){0.f, 0.f, 0.f, 0.f};

#pragma unroll
    for (int kc = 0; kc < 4; kc++) {
        const int k0 = kc * 32 + quad * 8;
        short8 xf[2];
#pragma unroll
        for (int nt = 0; nt < 2; nt++) {
            int nd = nt ? nodeB : nodeA;
            short8 v = (short8){0, 0, 0, 0, 0, 0, 0, 0};
            if (nd < n) {
                float4 f0 = *(const float4*)(Xf + (size_t)nd * 128 + k0);
                float4 f1 = *(const float4*)(Xf + (size_t)nd * 128 + k0 + 4);
                v[0] = (short)bf16rne(f0.x); v[1] = (short)bf16rne(f0.y);
                v[2] = (short)bf16rne(f0.z); v[3] = (short)bf16rne(f0.w);
                v[4] = (short)bf16rne(f1.x); v[5] = (short)bf16rne(f1.y);
                v[6] = (short)bf16rne(f1.z); v[7] = (short)bf16rne(f1.w);
            }
            xf[nt] = v;
        }
#pragma unroll
        for (int t = 0; t < 8; t++) {
            short8 w = *(const short8*)&sW[(t * 16 + m) * 136 + k0];
            acc[0][t] = __builtin_amdgcn_mfma_f32_16x16x32_bf16(w, xf[0], acc[0][t], 0, 0, 0);
            acc[1][t] = __builtin_amdgcn_mfma_f32_16x16x32_bf16(w, xf[1], acc[1][t], 0, 0, 0);
        }
    }

#pragma unroll
    for (int nt = 0; nt < 2; nt++) {
        int nd = nt ? nodeB : nodeA;
        if (nd >= n) continue;
        float dv = dinv[nd];
#pragma unroll
        for (int t = 0; t < 8; t++) {
            uint2 o;
            o.x = (unsigned int)bf16rne(acc[nt][t][0] * dv) |
                  ((unsigned int)bf16rne(acc[nt][t][1] * dv) << 16);
            o.y = (unsigned int)bf16rne(acc[nt][t][2] * dv) |
                  ((unsigned int)bf16rne(acc[nt][t][3] * dv) << 16);
            *(uint2*)&Yb[(size_t)nd * 128 + t * 16 + quad * 4] = o;
        }
    }
}

// ---- FUSED gather + next-layer GEMM: 32 nodes/block, 512 threads ----------
// (r6-proven: 74.6 us; 16-node variant regressed in r8 from doubled W L2
// traffic.) W read direct from global (L2-resident). LDS = sH only.
__global__ __launch_bounds__(512) void fused_gg(const uint2* __restrict__ cursor2,
                                                const uint2* __restrict__ sedge,
                                                const unsigned short* __restrict__ xin,
                                                const float* __restrict__ dinv,
                                                const float* __restrict__ bias,
                                                const unsigned short* __restrict__ Wt,
                                                unsigned short* __restrict__ xout) {
    __shared__ unsigned short sH[32 * 168];    // 10752 B
    const int tid = threadIdx.x;

    // ---- gather phase (r2-proven body) ----
    const int ln   = tid >> 4;              // local node 0..31
    const int node = blockIdx.x * 32 + ln;  // grid exact: always < N_NODES
    const int lane = tid & 15;
    uint2 cu = cursor2[node];
    int e = (int)cu.x, end = (int)cu.y;
    const uint4* tab = (const uint4*)xin;

    uint4 q0 = tab[(size_t)node * 16 + lane];
    float4 aL, aH;
    aL.x = blo(q0.x); aL.y = bhi(q0.x); aL.z = blo(q0.y); aL.w = bhi(q0.y);
    aH.x = blo(q0.z); aH.y = bhi(q0.z); aH.z = blo(q0.w); aH.w = bhi(q0.w);

    for (; e + 4 <= end; e += 4) {
        uint2 E[4]; uint4 q[4];
#pragma unroll
        for (int j = 0; j < 4; j++) E[j] = sedge[e + j];
#pragma unroll
        for (int j = 0; j < 4; j++) q[j] = tab[(size_t)E[j].x * 16 + lane];
#pragma unroll
        for (int j = 0; j < 4; j++) {
            float w = __uint_as_float(E[j].y);
            aL.x += w * blo(q[j].x); aL.y += w * bhi(q[j].x);
            aL.z += w * blo(q[j].y); aL.w += w * bhi(q[j].y);
            aH.x += w * blo(q[j].z); aH.y += w * bhi(q[j].z);
            aH.z += w * blo(q[j].w); aH.w += w * bhi(q[j].w);
        }
    }
    for (; e < end; ++e) {
        uint2 E = sedge[e];
        float w = __uint_as_float(E.y);
        uint4 q = tab[(size_t)E.x * 16 + lane];
        aL.x += w * blo(q.x); aL.y += w * bhi(q.x);
        aL.z += w * blo(q.y); aL.w += w * bhi(q.y);
        aH.x += w * blo(q.z); aH.y += w * bhi(q.z);
        aH.z += w * blo(q.w); aH.w += w * bhi(q.w);
    }

    {
        float d = dinv[node];
        float4 b0 = ((const float4*)bias)[lane * 2];
        float4 b1 = ((const float4*)bias)[lane * 2 + 1];
        aL.x = fmaxf(fmaf(d, aL.x, b0.x), 0.f);
        aL.y = fmaxf(fmaf(d, aL.y, b0.y), 0.f);
        aL.z = fmaxf(fmaf(d, aL.z, b0.z), 0.f);
        aL.w = fmaxf(fmaf(d, aL.w, b0.w), 0.f);
        aH.x = fmaxf(fmaf(d, aH.x, b1.x), 0.f);
        aH.y = fmaxf(fmaf(d, aH.y, b1.y), 0.f);
        aH.z = fmaxf(fmaf(d, aH.z, b1.z), 0.f);
        aH.w = fmaxf(fmaf(d, aH.w, b1.w), 0.f);
        uint4 o;
        o.x = (unsigned int)bf16rne(aL.x) | ((unsigned int)bf16rne(aL.y) << 16);
        o.y = (unsigned int)bf16rne(aL.z) | ((unsigned int)bf16rne(aL.w) << 16);
        o.z = (unsigned int)bf16rne(aH.x) | ((unsigned int)bf16rne(aH.y) << 16);
        o.w = (unsigned int)bf16rne(aH.z) | ((unsigned int)bf16rne(aH.w) << 16);
        *(uint4*)&sH[ln * 168 + lane * 8] = o;   // h[ln] channels lane*8..+7
    }
    __syncthreads();

    // ---- MFMA phase: wave w covers outcols w*16..+15, all 32 nodes ----
    const int wave = tid >> 6;
    const int l64  = tid & 63;
    const int m    = l64 & 15, quad = l64 >> 4;

    float4v acc0 = (float4v){0.f, 0.f, 0.f, 0.f};
    float4v acc1 = (float4v){0.f, 0.f, 0.f, 0.f};

#pragma unroll
    for (int kc = 0; kc < 4; kc++) {
        const int k0 = kc * 32 + quad * 8;
        short8 wf = *(const short8*)&Wt[(size_t)(wave * 16 + m) * 128 + k0];
        short8 h0 = *(const short8*)&sH[m * 168 + k0];
        short8 h1 = *(const short8*)&sH[(16 + m) * 168 + k0];
        acc0 = __builtin_amdgcn_mfma_f32_16x16x32_bf16(wf, h0, acc0, 0, 0, 0);
        acc1 = __builtin_amdgcn_mfma_f32_16x16x32_bf16(wf, h1, acc1, 0, 0, 0);
    }

#pragma unroll
    for (int nt = 0; nt < 2; nt++) {
        int nd = blockIdx.x * 32 + nt * 16 + m;
        float dv = dinv[nd];
        float4v a = nt ? acc1 : acc0;
        uint2 o;
        o.x = (unsigned int)bf16rne(a[0] * dv) |
              ((unsigned int)bf16rne(a[1] * dv) << 16);
        o.y = (unsigned int)bf16rne(a[2] * dv) |
              ((unsigned int)bf16rne(a[3] * dv) << 16);
        *(uint2*)&xout[(size_t)nd * 128 + wave * 16 + quad * 4] = o;
    }
}

// -------- CSR gather (final layer): fused linear output --------------------
__global__ __launch_bounds__(256) void gather_csr(const uint2* __restrict__ cursor2,
                                                  const uint2* __restrict__ sedge,
                                                  const unsigned short* __restrict__ xwb,
                                                  const float* __restrict__ dinv,
                                                  const float* __restrict__ bias,
                                                  float* __restrict__ outp,
                                                  const float* __restrict__ lw,
                                                  const float* __restrict__ lb) {
    int node = blockIdx.x * 16 + (threadIdx.x >> 4);
    int lane = threadIdx.x & 15;
    if (node >= N_NODES) return;
    uint2 cu = cursor2[node];
    int e = (int)cu.x, end = (int)cu.y;
    const uint4* tab = (const uint4*)xwb;

    uint4 q0 = tab[(size_t)node * 16 + lane];
    float4 aL, aH;
    aL.x = blo(q0.x); aL.y = bhi(q0.x); aL.z = blo(q0.y); aL.w = bhi(q0.y);
    aH.x = blo(q0.z); aH.y = bhi(q0.z); aH.z = blo(q0.w); aH.w = bhi(q0.w);

    for (; e + 4 <= end; e += 4) {
        uint2 E[4]; uint4 q[4];
#pragma unroll
        for (int j = 0; j < 4; j++) E[j] = sedge[e + j];
#pragma unroll
        for (int j = 0; j < 4; j++) q[j] = tab[(size_t)E[j].x * 16 + lane];
#pragma unroll
        for (int j = 0; j < 4; j++) {
            float w = __uint_as_float(E[j].y);
            aL.x += w * blo(q[j].x); aL.y += w * bhi(q[j].x);
            aL.z += w * blo(q[j].y); aL.w += w * bhi(q[j].y);
            aH.x += w * blo(q[j].z); aH.y += w * bhi(q[j].z);
            aH.z += w * blo(q[j].w); aH.w += w * bhi(q[j].w);
        }
    }
    for (; e < end; ++e) {
        uint2 E = sedge[e];
        float w = __uint_as_float(E.y);
        uint4 q = tab[(size_t)E.x * 16 + lane];
        aL.x += w * blo(q.x); aL.y += w * bhi(q.x);
        aL.z += w * blo(q.y); aL.w += w * bhi(q.y);
        aH.x += w * blo(q.z); aH.y += w * bhi(q.z);
        aH.z += w * blo(q.w); aH.w += w * bhi(q.w);
    }

    float d = dinv[node];
    float4 b0 = ((const float4*)bias)[lane * 2];
    float4 b1 = ((const float4*)bias)[lane * 2 + 1];
    aL.x = fmaxf(fmaf(d, aL.x, b0.x), 0.f);
    aL.y = fmaxf(fmaf(d, aL.y, b0.y), 0.f);
    aL.z = fmaxf(fmaf(d, aL.z, b0.z), 0.f);
    aL.w = fmaxf(fmaf(d, aL.w, b0.w), 0.f);
    aH.x = fmaxf(fmaf(d, aH.x, b1.x), 0.f);
    aH.y = fmaxf(fmaf(d, aH.y, b1.y), 0.f);
    aH.z = fmaxf(fmaf(d, aH.z, b1.z), 0.f);
    aH.w = fmaxf(fmaf(d, aH.w, b1.w), 0.f);

    float4 w0 = ((const float4*)lw)[lane * 2];
    float4 w1 = ((const float4*)lw)[lane * 2 + 1];
    float p = aL.x * w0.x + aL.y * w0.y + aL.z * w0.z + aL.w * w0.w +
              aH.x * w1.x + aH.y * w1.y + aH.z * w1.z + aH.w * w1.w;
#pragma unroll
    for (int off = 8; off; off >>= 1) p += __shfl_down(p, off);
    if (lane == 0) outp[node] = p + lb[0];
}

extern "C" void kernel_launch(void* const* d_in, const int* in_sizes, int n_in,
                              void* d_out, int out_size, void* d_ws, size_t ws_size,
                              hipStream_t stream) {
    const float* x   = (const float*)d_in[0];
    const int*   ei  = (const int*)d_in[1];   // int64 in reference -> int32 on device
    const float* ea  = (const float*)d_in[2];
    const float* W1  = (const float*)d_in[3];
    const float* b1  = (const float*)d_in[4];
    const float* W2  = (const float*)d_in[5];
    const float* b2  = (const float*)d_in[6];
    const float* W3  = (const float*)d_in[7];
    const float* b3  = (const float*)d_in[8];
    const float* lw  = (const float*)d_in[9];
    const float* lb  = (const float*)d_in[10];
    float*       out = (float*)d_out;

    const int* row = ei;        // edge_index[0]
    const int* col = ei + NE;   // edge_index[1]

    const int BS = 256;
    int gGather = (N_NODES + 15) / 16;    // 6250
    int gFused  = N_NODES / 32;           // 3125, exact
    int gGemm   = (N_NODES + 127) / 128;

    // workspace layout (~81 MB), 16B-aligned blocks:
    //   babuf uint2[NBLKA*EPB] | sedge uint2[NB*BCAP] | cursor2 uint2[N] |
    //   dinv f[N] | hcntg i[NB*NBLKA] | Wt u16[3*16384] | xwbA | xwbB
    char* wsb = (char*)d_ws;
    uint2*          babuf   = (uint2*)wsb;          wsb += (size_t)NBLKA * EPB * 8;
    uint2*          sedge   = (uint2*)wsb;          wsb += (size_t)NB * BCAP * 8;
    uint2*          cursor2 = (uint2*)wsb;          wsb += (size_t)N_NODES * 8;
    float*          dinv    = (float*)wsb;          wsb += (size_t)N_NODES * 4;
    int*            hcntg   = (int*)wsb;            wsb += (size_t)NB * NBLKA * 4 + 64;
    unsigned short* Wt      = (unsigned short*)wsb; wsb += 3 * 16384 * 2;
    unsigned short* xwbA    = (unsigned short*)wsb; wsb += (size_t)N_NODES * C * 2;
    unsigned short* xwbB    = (unsigned short*)wsb;

    binA_kernel<<<NBLKA + 1, BS, 0, stream>>>(row, col, ea, hcntg, babuf,
                                              W1, W2, W3, Wt);
    binB_kernel<<<NB, 1024, 0, stream>>>(hcntg, babuf, dinv, cursor2, sedge);

    // layer 1 projection (fp32 input): x @ W1 -> xwbA
    gemm_mfma<<<gGemm, BS, 0, stream>>>(x, Wt, dinv, xwbA, N_NODES);
    // layer 1 gather + layer 2 projection (fused): -> xwbB
    fused_gg<<<gFused, 512, 0, stream>>>(cursor2, sedge, xwbA, dinv, b1,
                                         Wt + 16384, xwbB);
    // layer 2 gather + layer 3 projection (fused): -> xwbA
    fused_gg<<<gFused, 512, 0, stream>>>(cursor2, sedge, xwbB, dinv, b2,
                                         Wt + 32768, xwbA);
    // layer 3 gather + final linear
    gather_csr<<<gGather, BS, 0, stream>>>(cursor2, sedge, xwbA, dinv, b3,
                                           out, lw, lb);
}

// Round 10
// 368.569 us; speedup vs baseline: 1.2482x; 1.2482x over previous
//
#include <hip/hip_runtime.h>

#define N_NODES 100000
#define NE      1600000
#define C       128
#define NB      98        // buckets of 1024 destination nodes
#define BCAP    19968     // per-bucket capacity; mean 16327, ~28-sigma margin
#define EPB     4096      // edges per binA block
#define NBLKA   391       // ceil(NE/EPB)
#define GSTRIDE 32        // gbcur padding: 1 counter per 128 B line
#define GEMMB   782       // ceil(N/128)

typedef __attribute__((ext_vector_type(8))) short short8;
typedef __attribute__((ext_vector_type(4))) float float4v;

__device__ __forceinline__ unsigned short bf16rne(float f) {
    unsigned int u = __float_as_uint(f);
    return (unsigned short)((u + 0x7FFFu + ((u >> 16) & 1u)) >> 16);
}
__device__ __forceinline__ float blo(unsigned int u) { return __uint_as_float(u << 16); }
__device__ __forceinline__ float bhi(unsigned int u) { return __uint_as_float(u & 0xFFFF0000u); }

// ---- combined prologue dispatch: binA buckets | wt3 | layer-1 GEMM --------
// Roles by blockIdx: [0,391) binA (r2/r8-proven, bucket-grouped babuf via
// padded global-atomic alloc); ==391 wt3 (W2,W3 transpose; W1 slot too,
// harmless); >391 layer-1 GEMM (self-stages W1 fp32->bf16 transposed in LDS,
// writes xwbA UNSCALED -- dinv moved to gather side, so no binB dependency).
// Big LDS regions manually overlaid: binA recs+gdst (48 KB) | gemm sW (34 KB).
__global__ __launch_bounds__(256) void binA_kernel(const int* __restrict__ row,
                                                   const int* __restrict__ col,
                                                   const float* __restrict__ ew,
                                                   int* __restrict__ gbcur,
                                                   uint2* __restrict__ babuf,
                                                   const float* __restrict__ W1,
                                                   const float* __restrict__ W2,
                                                   const float* __restrict__ W3,
                                                   unsigned short* __restrict__ Wt,
                                                   const float* __restrict__ Xf,
                                                   unsigned short* __restrict__ Yb) {
    __shared__ __align__(16) char big[49152];   // recs(32K)+gdst(16K) | sW(34.8K)
    __shared__ int hcnt[NB];
    __shared__ int hofs[NB];
    __shared__ int hbase[NB];
    __shared__ int lofs[NB];
    __shared__ int scn[128];
    const int t = threadIdx.x;

    if (blockIdx.x == NBLKA) {   // ---- wt3: Wt[l][n][k] = bf16(Wl[k][n]) ----
        for (int i = t; i < 3 * 16384; i += 256) {
            int layer = i >> 14, r = i & 16383;
            int n = r >> 7, k = r & 127;
            const float* W = layer == 0 ? W1 : (layer == 1 ? W2 : W3);
            Wt[i] = bf16rne(W[k * 128 + n]);
        }
        return;
    }

    if (blockIdx.x > NBLKA) {    // ---- layer-1 GEMM (no dinv dependency) ----
        unsigned short* sW = (unsigned short*)big;   // [outcol][k], stride 136
        // stage W1 transposed: coalesced global fp32 reads, strided LDS writes
        for (int i = t; i < 16384; i += 256) {
            int k = i >> 7, n = i & 127;
            sW[n * 136 + k] = bf16rne(W1[i]);
        }
        __syncthreads();

        const int wave = t >> 6, lane = t & 63;
        const int m = lane & 15, quad = lane >> 4;
        const int node0 = (blockIdx.x - NBLKA - 1) * 128 + wave * 32;
        const int nodeA = node0 + m;
        const int nodeB = node0 + 16 + m;

        float4v acc[2][8];
#pragma unroll
        for (int nt = 0; nt < 2; nt++)
#pragma unroll
            for (int tt = 0; tt < 8; tt++) acc[nt][tt] = (float4v){0.f, 0.f, 0.f, 0.f};

#pragma unroll
        for (int kc = 0; kc < 4; kc++) {
            const int k0 = kc * 32 + quad * 8;
            short8 xf[2];
#pragma unroll
            for (int nt = 0; nt < 2; nt++) {
                int nd = nt ? nodeB : nodeA;
                short8 v = (short8){0, 0, 0, 0, 0, 0, 0, 0};
                if (nd < N_NODES) {
                    float4 f0 = *(const float4*)(Xf + (size_t)nd * 128 + k0);
                    float4 f1 = *(const float4*)(Xf + (size_t)nd * 128 + k0 + 4);
                    v[0] = (short)bf16rne(f0.x); v[1] = (short)bf16rne(f0.y);
                    v[2] = (short)bf16rne(f0.z); v[3] = (short)bf16rne(f0.w);
                    v[4] = (short)bf16rne(f1.x); v[5] = (short)bf16rne(f1.y);
                    v[6] = (short)bf16rne(f1.z); v[7] = (short)bf16rne(f1.w);
                }
                xf[nt] = v;
            }
#pragma unroll
            for (int tt = 0; tt < 8; tt++) {
                short8 w = *(const short8*)&sW[(tt * 16 + m) * 136 + k0];
                acc[0][tt] = __builtin_amdgcn_mfma_f32_16x16x32_bf16(w, xf[0], acc[0][tt], 0, 0, 0);
                acc[1][tt] = __builtin_amdgcn_mfma_f32_16x16x32_bf16(w, xf[1], acc[1][tt], 0, 0, 0);
            }
        }
#pragma unroll
        for (int nt = 0; nt < 2; nt++) {
            int nd = nt ? nodeB : nodeA;
            if (nd >= N_NODES) continue;
#pragma unroll
            for (int tt = 0; tt < 8; tt++) {
                uint2 o;
                o.x = (unsigned int)bf16rne(acc[nt][tt][0]) |
                      ((unsigned int)bf16rne(acc[nt][tt][1]) << 16);
                o.y = (unsigned int)bf16rne(acc[nt][tt][2]) |
                      ((unsigned int)bf16rne(acc[nt][tt][3]) << 16);
                *(uint2*)&Yb[(size_t)nd * 128 + tt * 16 + quad * 4] = o;
            }
        }
        return;
    }

    // ---- binA (r8-proven) ----
    uint2* recs = (uint2*)big;              // 32 KB
    int*   gdst = (int*)(big + 32768);      // 16 KB
    for (int i = t; i < NB; i += 256) { hcnt[i] = 0; hofs[i] = 0; }
    __syncthreads();

    const int e0 = blockIdx.x * EPB;
    int cc[16], rr[16]; float ee[16];
#pragma unroll
    for (int i = 0; i < 16; i++) {
        int e = e0 + i * 256 + t;
        if (e < NE) { cc[i] = col[e]; rr[i] = row[e]; ee[i] = ew[e]; }
        else cc[i] = -1;
    }
#pragma unroll
    for (int i = 0; i < 16; i++)
        if (cc[i] >= 0) atomicAdd(&hcnt[cc[i] >> 10], 1);
    __syncthreads();
    if (t < NB) {
        int c = hcnt[t];
        hbase[t] = c ? atomicAdd(&gbcur[t * GSTRIDE], c) : 0;
    }
    if (t < 128) scn[t] = (t < NB) ? hcnt[t] : 0;
    __syncthreads();
    for (int off = 1; off < 128; off <<= 1) {
        int v = 0;
        if (t < 128 && t >= off) v = scn[t - off];
        __syncthreads();
        if (t < 128) scn[t] += v;
        __syncthreads();
    }
    if (t < NB) lofs[t] = scn[t] - hcnt[t];
    __syncthreads();
#pragma unroll
    for (int i = 0; i < 16; i++) {
        if (cc[i] < 0) continue;
        int b = cc[i] >> 10;
        int lpos = atomicAdd(&hofs[b], 1);
        int si = lofs[b] + lpos;
        unsigned int meta = ((unsigned int)(cc[i] & 1023) << 17) | (unsigned int)rr[i];
        recs[si] = make_uint2(meta, __float_as_uint(ee[i]));
        int gp = hbase[b] + lpos;
        gdst[si] = (gp < BCAP) ? (b * BCAP + gp) : -1;
    }
    __syncthreads();
    const int valid = lofs[NB - 1] + hcnt[NB - 1];
    for (int i = t; i < valid; i += 256) {
        int g = gdst[i];
        if (g >= 0) babuf[g] = recs[i];
    }
}

// ---- binB: single-pass per-bucket build (r8-proven) -----------------------
__global__ __launch_bounds__(1024) void binB_kernel(const int* __restrict__ gbcur,
                                                    const uint2* __restrict__ babuf,
                                                    float* __restrict__ dinv,
                                                    uint2* __restrict__ cursor2,
                                                    uint2* __restrict__ sedge) {
    __shared__ unsigned long long pk[1024];   // 8 KB
    __shared__ int ofs[1024];
    __shared__ int wtot[16];
    const int b = blockIdx.x, t = threadIdx.x;
    const int n0 = b << 10;
    const int nn = min(1024, N_NODES - n0);

    pk[t] = 0ull;
    __syncthreads();

    const int msize = min(gbcur[b * GSTRIDE], BCAP);
    const int nslots = (msize + 1023) >> 10;
    const uint2* bb = babuf + (size_t)b * BCAP;
    uint2 rec[20];
#pragma unroll
    for (int slot = 0; slot < 20; slot++) {
        int i = (slot << 10) + t;
        bool v = (slot < nslots) && (i < msize);
        uint2 m = v ? bb[i] : make_uint2(0u, 0u);
        rec[slot] = m;
        if (v) {
            unsigned long long add = (1ull << 44) +
                (unsigned long long)(__uint_as_float(m.y) * 4294967296.0f);
            atomicAdd(&pk[m.x >> 17], add);
        }
    }
    __syncthreads();

    const unsigned long long p = pk[t];
    const int myc = (int)(p >> 44);
    const float deg = (float)(p & ((1ull << 44) - 1)) * (1.0f / 4294967296.0f);
    if (t < nn) dinv[n0 + t] = 1.0f / sqrtf(deg + 1.0f);

    const int lane64 = t & 63, w = t >> 6;
    int s = myc;
#pragma unroll
    for (int off = 1; off < 64; off <<= 1) {
        int u = __shfl_up(s, off);
        if (lane64 >= off) s += u;
    }
    if (lane64 == 63) wtot[w] = s;
    __syncthreads();
    if (t < 16) {
        int u = wtot[t];
#pragma unroll
        for (int off = 1; off < 16; off <<= 1) {
            int uu = __shfl_up(u, off);
            if (t >= off) u += uu;
        }
        wtot[t] = u;
    }
    __syncthreads();
    const int excl = s + (w ? wtot[w - 1] : 0) - myc;
    ofs[t] = excl;

    const unsigned int ebase = (unsigned int)b * BCAP;
    if (t < nn) {
        unsigned int st = ebase + (unsigned int)excl;
        cursor2[n0 + t] = make_uint2(st, st + (unsigned int)myc);
    }
    __syncthreads();

#pragma unroll
    for (int slot = 0; slot < 20; slot++) {
        int i = (slot << 10) + t;
        bool v = (slot < nslots) && (i < msize);
        if (v) {
            uint2 m = rec[slot];
            int cl = m.x >> 17;
            int pp = atomicAdd(&ofs[cl], 1);
            sedge[(size_t)b * BCAP + pp] = make_uint2(m.x & 0x1FFFFu, m.y);
        }
    }
}

// ---- FUSED gather + next-layer GEMM: 32 nodes/block, 512 threads ----------
// xin/xout are UNSCALED (xw). Row-norm applied per edge: w = ew*dinv[r]
// (dinv L2-resident, uniform across the 16-lane group). Self term dv*tab[c].
__global__ __launch_bounds__(512) void fused_gg(const uint2* __restrict__ cursor2,
                                                const uint2* __restrict__ sedge,
                                                const unsigned short* __restrict__ xin,
                                                const float* __restrict__ dinv,
                                                const float* __restrict__ bias,
                                                const unsigned short* __restrict__ Wt,
                                                unsigned short* __restrict__ xout) {
    __shared__ unsigned short sH[32 * 168];    // 10752 B
    const int tid = threadIdx.x;

    const int ln   = tid >> 4;              // local node 0..31
    const int node = blockIdx.x * 32 + ln;  // grid exact
    const int lane = tid & 15;
    uint2 cu = cursor2[node];
    int e = (int)cu.x, end = (int)cu.y;
    const uint4* tab = (const uint4*)xin;

    const float dv = dinv[node];
    uint4 q0 = tab[(size_t)node * 16 + lane];
    float4 aL, aH;
    aL.x = dv * blo(q0.x); aL.y = dv * bhi(q0.x);
    aL.z = dv * blo(q0.y); aL.w = dv * bhi(q0.y);
    aH.x = dv * blo(q0.z); aH.y = dv * bhi(q0.z);
    aH.z = dv * blo(q0.w); aH.w = dv * bhi(q0.w);

    for (; e + 4 <= end; e += 4) {
        uint2 E[4]; uint4 q[4]; float dr[4];
#pragma unroll
        for (int j = 0; j < 4; j++) E[j] = sedge[e + j];
#pragma unroll
        for (int j = 0; j < 4; j++) { q[j] = tab[(size_t)E[j].x * 16 + lane]; dr[j] = dinv[E[j].x]; }
#pragma unroll
        for (int j = 0; j < 4; j++) {
            float w = __uint_as_float(E[j].y) * dr[j];
            aL.x += w * blo(q[j].x); aL.y += w * bhi(q[j].x);
            aL.z += w * blo(q[j].y); aL.w += w * bhi(q[j].y);
            aH.x += w * blo(q[j].z); aH.y += w * bhi(q[j].z);
            aH.z += w * blo(q[j].w); aH.w += w * bhi(q[j].w);
        }
    }
    for (; e < end; ++e) {
        uint2 E = sedge[e];
        float w = __uint_as_float(E.y) * dinv[E.x];
        uint4 q = tab[(size_t)E.x * 16 + lane];
        aL.x += w * blo(q.x); aL.y += w * bhi(q.x);
        aL.z += w * blo(q.y); aL.w += w * bhi(q.y);
        aH.x += w * blo(q.z); aH.y += w * bhi(q.z);
        aH.z += w * blo(q.w); aH.w += w * bhi(q.w);
    }

    {
        float4 b0 = ((const float4*)bias)[lane * 2];
        float4 b1 = ((const float4*)bias)[lane * 2 + 1];
        aL.x = fmaxf(fmaf(dv, aL.x, b0.x), 0.f);
        aL.y = fmaxf(fmaf(dv, aL.y, b0.y), 0.f);
        aL.z = fmaxf(fmaf(dv, aL.z, b0.z), 0.f);
        aL.w = fmaxf(fmaf(dv, aL.w, b0.w), 0.f);
        aH.x = fmaxf(fmaf(dv, aH.x, b1.x), 0.f);
        aH.y = fmaxf(fmaf(dv, aH.y, b1.y), 0.f);
        aH.z = fmaxf(fmaf(dv, aH.z, b1.z), 0.f);
        aH.w = fmaxf(fmaf(dv, aH.w, b1.w), 0.f);
        uint4 o;
        o.x = (unsigned int)bf16rne(aL.x) | ((unsigned int)bf16rne(aL.y) << 16);
        o.y = (unsigned int)bf16rne(aL.z) | ((unsigned int)bf16rne(aL.w) << 16);
        o.z = (unsigned int)bf16rne(aH.x) | ((unsigned int)bf16rne(aH.y) << 16);
        o.w = (unsigned int)bf16rne(aH.z) | ((unsigned int)bf16rne(aH.w) << 16);
        *(uint4*)&sH[ln * 168 + lane * 8] = o;
    }
    __syncthreads();

    // ---- MFMA phase: wave w covers outcols w*16..+15, all 32 nodes ----
    const int wave = tid >> 6;
    const int l64  = tid & 63;
    const int m    = l64 & 15, quad = l64 >> 4;

    float4v acc0 = (float4v){0.f, 0.f, 0.f, 0.f};
    float4v acc1 = (float4v){0.f, 0.f, 0.f, 0.f};

#pragma unroll
    for (int kc = 0; kc < 4; kc++) {
        const int k0 = kc * 32 + quad * 8;
        short8 wf = *(const short8*)&Wt[(size_t)(wave * 16 + m) * 128 + k0];
        short8 h0 = *(const short8*)&sH[m * 168 + k0];
        short8 h1 = *(const short8*)&sH[(16 + m) * 168 + k0];
        acc0 = __builtin_amdgcn_mfma_f32_16x16x32_bf16(wf, h0, acc0, 0, 0, 0);
        acc1 = __builtin_amdgcn_mfma_f32_16x16x32_bf16(wf, h1, acc1, 0, 0, 0);
    }

#pragma unroll
    for (int nt = 0; nt < 2; nt++) {
        int nd = blockIdx.x * 32 + nt * 16 + m;
        float4v a = nt ? acc1 : acc0;
        uint2 o;
        o.x = (unsigned int)bf16rne(a[0]) | ((unsigned int)bf16rne(a[1]) << 16);
        o.y = (unsigned int)bf16rne(a[2]) | ((unsigned int)bf16rne(a[3]) << 16);
        *(uint2*)&xout[(size_t)nd * 128 + wave * 16 + quad * 4] = o;
    }
}

// -------- CSR gather (final layer): fused linear output --------------------
__global__ __launch_bounds__(256) void gather_csr(const uint2* __restrict__ cursor2,
                                                  const uint2* __restrict__ sedge,
                                                  const unsigned short* __restrict__ xwb,
                                                  const float* __restrict__ dinv,
                                                  const float* __restrict__ bias,
                                                  float* __restrict__ outp,
                                                  const float* __restrict__ lw,
                                                  const float* __restrict__ lb) {
    int node = blockIdx.x * 16 + (threadIdx.x >> 4);
    int lane = threadIdx.x & 15;
    if (node >= N_NODES) return;
    uint2 cu = cursor2[node];
    int e = (int)cu.x, end = (int)cu.y;
    const uint4* tab = (const uint4*)xwb;

    const float dv = dinv[node];
    uint4 q0 = tab[(size_t)node * 16 + lane];
    float4 aL, aH;
    aL.x = dv * blo(q0.x); aL.y = dv * bhi(q0.x);
    aL.z = dv * blo(q0.y); aL.w = dv * bhi(q0.y);
    aH.x = dv * blo(q0.z); aH.y = dv * bhi(q0.z);
    aH.z = dv * blo(q0.w); aH.w = dv * bhi(q0.w);

    for (; e + 4 <= end; e += 4) {
        uint2 E[4]; uint4 q[4]; float dr[4];
#pragma unroll
        for (int j = 0; j < 4; j++) E[j] = sedge[e + j];
#pragma unroll
        for (int j = 0; j < 4; j++) { q[j] = tab[(size_t)E[j].x * 16 + lane]; dr[j] = dinv[E[j].x]; }
#pragma unroll
        for (int j = 0; j < 4; j++) {
            float w = __uint_as_float(E[j].y) * dr[j];
            aL.x += w * blo(q[j].x); aL.y += w * bhi(q[j].x);
            aL.z += w * blo(q[j].y); aL.w += w * bhi(q[j].y);
            aH.x += w * blo(q[j].z); aH.y += w * bhi(q[j].z);
            aH.z += w * blo(q[j].w); aH.w += w * bhi(q[j].w);
        }
    }
    for (; e < end; ++e) {
        uint2 E = sedge[e];
        float w = __uint_as_float(E.y) * dinv[E.x];
        uint4 q = tab[(size_t)E.x * 16 + lane];
        aL.x += w * blo(q.x); aL.y += w * bhi(q.x);
        aL.z += w * blo(q.y); aL.w += w * bhi(q.y);
        aH.x += w * blo(q.z); aH.y += w * bhi(q.z);
        aH.z += w * blo(q.w); aH.w += w * bhi(q.w);
    }

    float4 b0 = ((const float4*)bias)[lane * 2];
    float4 b1 = ((const float4*)bias)[lane * 2 + 1];
    aL.x = fmaxf(fmaf(dv, aL.x, b0.x), 0.f);
    aL.y = fmaxf(fmaf(dv, aL.y, b0.y), 0.f);
    aL.z = fmaxf(fmaf(dv, aL.z, b0.z), 0.f);
    aL.w = fmaxf(fmaf(dv, aL.w, b0.w), 0.f);
    aH.x = fmaxf(fmaf(dv, aH.x, b1.x), 0.f);
    aH.y = fmaxf(fmaf(dv, aH.y, b1.y), 0.f);
    aH.z = fmaxf(fmaf(dv, aH.z, b1.z), 0.f);
    aH.w = fmaxf(fmaf(dv, aH.w, b1.w), 0.f);

    float4 w0 = ((const float4*)lw)[lane * 2];
    float4 w1 = ((const float4*)lw)[lane * 2 + 1];
    float p = aL.x * w0.x + aL.y * w0.y + aL.z * w0.z + aL.w * w0.w +
              aH.x * w1.x + aH.y * w1.y + aH.z * w1.z + aH.w * w1.w;
#pragma unroll
    for (int off = 8; off; off >>= 1) p += __shfl_down(p, off);
    if (lane == 0) outp[node] = p + lb[0];
}

extern "C" void kernel_launch(void* const* d_in, const int* in_sizes, int n_in,
                              void* d_out, int out_size, void* d_ws, size_t ws_size,
                              hipStream_t stream) {
    const float* x   = (const float*)d_in[0];
    const int*   ei  = (const int*)d_in[1];   // int64 in reference -> int32 on device
    const float* ea  = (const float*)d_in[2];
    const float* W1  = (const float*)d_in[3];
    const float* b1  = (const float*)d_in[4];
    const float* W2  = (const float*)d_in[5];
    const float* b2  = (const float*)d_in[6];
    const float* W3  = (const float*)d_in[7];
    const float* b3  = (const float*)d_in[8];
    const float* lw  = (const float*)d_in[9];
    const float* lb  = (const float*)d_in[10];
    float*       out = (float*)d_out;

    const int* row = ei;        // edge_index[0]
    const int* col = ei + NE;   // edge_index[1]

    const int BS = 256;
    int gGather = (N_NODES + 15) / 16;    // 6250
    int gFused  = N_NODES / 32;           // 3125, exact
    int gCombo  = NBLKA + 1 + GEMMB;      // 391 binA + 1 wt3 + 782 gemm

    // workspace layout (~84 MB):
    //   babuf uint2[NB*BCAP] | sedge uint2[NB*BCAP] | cursor2 uint2[N] |
    //   dinv f[N] | gbcur i[128*GSTRIDE] | Wt u16[3*16384] | xwbA | xwbB
    char* wsb = (char*)d_ws;
    uint2*          babuf   = (uint2*)wsb;          wsb += (size_t)NB * BCAP * 8;
    uint2*          sedge   = (uint2*)wsb;          wsb += (size_t)NB * BCAP * 8;
    uint2*          cursor2 = (uint2*)wsb;          wsb += (size_t)N_NODES * 8;
    float*          dinv    = (float*)wsb;          wsb += (size_t)N_NODES * 4;
    int*            gbcur   = (int*)wsb;            wsb += 128 * GSTRIDE * 4;
    unsigned short* Wt      = (unsigned short*)wsb; wsb += 3 * 16384 * 2;
    unsigned short* xwbA    = (unsigned short*)wsb; wsb += (size_t)N_NODES * C * 2;
    unsigned short* xwbB    = (unsigned short*)wsb;

    hipMemsetAsync(gbcur, 0, 128 * GSTRIDE * 4, stream);
    // combined: binA buckets + wt3 + layer-1 gemm (gemm is dinv-independent)
    binA_kernel<<<gCombo, BS, 0, stream>>>(row, col, ea, gbcur, babuf,
                                           W1, W2, W3, Wt, x, xwbA);
    binB_kernel<<<NB, 1024, 0, stream>>>(gbcur, babuf, dinv, cursor2, sedge);

    // layer 1 gather + layer 2 projection (fused): -> xwbB
    fused_gg<<<gFused, 512, 0, stream>>>(cursor2, sedge, xwbA, dinv, b1,
                                         Wt + 16384, xwbB);
    // layer 2 gather + layer 3 projection (fused): -> xwbA
    fused_gg<<<gFused, 512, 0, stream>>>(cursor2, sedge, xwbB, dinv, b2,
                                         Wt + 32768, xwbA);
    // layer 3 gather + final linear
    gather_csr<<<gGather, BS, 0, stream>>>(cursor2, sedge, xwbA, dinv, b3,
                                           out, lw, lb);
}

// Round 11
// 367.924 us; speedup vs baseline: 1.2503x; 1.0018x over previous
//
#include <hip/hip_runtime.h>

#define N_NODES 100000
#define NE      1600000
#define C       128
#define NB      98        // buckets of 1024 destination nodes
#define BCAP    19968     // per-bucket capacity; mean 16327, ~28-sigma margin
#define EPB     4096      // edges per binA block
#define NBLKA   391       // ceil(NE/EPB)
#define GSTRIDE 32        // gbcur padding: 1 counter per 128 B line
#define GEMMB   782       // ceil(N/128)

typedef __attribute__((ext_vector_type(8))) short short8;
typedef __attribute__((ext_vector_type(4))) float float4v;

__device__ __forceinline__ unsigned short bf16rne(float f) {
    unsigned int u = __float_as_uint(f);
    return (unsigned short)((u + 0x7FFFu + ((u >> 16) & 1u)) >> 16);
}
__device__ __forceinline__ float blo(unsigned int u) { return __uint_as_float(u << 16); }
__device__ __forceinline__ float bhi(unsigned int u) { return __uint_as_float(u & 0xFFFF0000u); }

// ---- combined prologue dispatch: binA buckets | wt3 | layer-1 GEMM --------
// Roles by blockIdx: [0,391) binA (bucket-grouped babuf via padded
// global-atomic alloc); ==391 wt3; >391 layer-1 GEMM (self-stages W1
// fp32->bf16 transposed in LDS, writes xwbA UNSCALED -- dinv applied on the
// gather side, so the GEMM has no binB dependency and overlaps the binning).
__global__ __launch_bounds__(256) void binA_kernel(const int* __restrict__ row,
                                                   const int* __restrict__ col,
                                                   const float* __restrict__ ew,
                                                   int* __restrict__ gbcur,
                                                   uint2* __restrict__ babuf,
                                                   const float* __restrict__ W1,
                                                   const float* __restrict__ W2,
                                                   const float* __restrict__ W3,
                                                   unsigned short* __restrict__ Wt,
                                                   const float* __restrict__ Xf,
                                                   unsigned short* __restrict__ Yb) {
    __shared__ __align__(16) char big[49152];   // recs(32K)+gdst(16K) | sW(34.8K)
    __shared__ int hcnt[NB];
    __shared__ int hofs[NB];
    __shared__ int hbase[NB];
    __shared__ int lofs[NB];
    __shared__ int scn[128];
    const int t = threadIdx.x;

    if (blockIdx.x == NBLKA) {   // ---- wt3: Wt[l][n][k] = bf16(Wl[k][n]) ----
        for (int i = t; i < 3 * 16384; i += 256) {
            int layer = i >> 14, r = i & 16383;
            int n = r >> 7, k = r & 127;
            const float* W = layer == 0 ? W1 : (layer == 1 ? W2 : W3);
            Wt[i] = bf16rne(W[k * 128 + n]);
        }
        return;
    }

    if (blockIdx.x > NBLKA) {    // ---- layer-1 GEMM (no dinv dependency) ----
        unsigned short* sW = (unsigned short*)big;   // [outcol][k], stride 136
        for (int i = t; i < 16384; i += 256) {
            int k = i >> 7, n = i & 127;
            sW[n * 136 + k] = bf16rne(W1[i]);
        }
        __syncthreads();

        const int wave = t >> 6, lane = t & 63;
        const int m = lane & 15, quad = lane >> 4;
        const int node0 = (blockIdx.x - NBLKA - 1) * 128 + wave * 32;
        const int nodeA = node0 + m;
        const int nodeB = node0 + 16 + m;

        float4v acc[2][8];
#pragma unroll
        for (int nt = 0; nt < 2; nt++)
#pragma unroll
            for (int tt = 0; tt < 8; tt++) acc[nt][tt] = (float4v){0.f, 0.f, 0.f, 0.f};

#pragma unroll
        for (int kc = 0; kc < 4; kc++) {
            const int k0 = kc * 32 + quad * 8;
            short8 xf[2];
#pragma unroll
            for (int nt = 0; nt < 2; nt++) {
                int nd = nt ? nodeB : nodeA;
                short8 v = (short8){0, 0, 0, 0, 0, 0, 0, 0};
                if (nd < N_NODES) {
                    float4 f0 = *(const float4*)(Xf + (size_t)nd * 128 + k0);
                    float4 f1 = *(const float4*)(Xf + (size_t)nd * 128 + k0 + 4);
                    v[0] = (short)bf16rne(f0.x); v[1] = (short)bf16rne(f0.y);
                    v[2] = (short)bf16rne(f0.z); v[3] = (short)bf16rne(f0.w);
                    v[4] = (short)bf16rne(f1.x); v[5] = (short)bf16rne(f1.y);
                    v[6] = (short)bf16rne(f1.z); v[7] = (short)bf16rne(f1.w);
                }
                xf[nt] = v;
            }
#pragma unroll
            for (int tt = 0; tt < 8; tt++) {
                short8 w = *(const short8*)&sW[(tt * 16 + m) * 136 + k0];
                acc[0][tt] = __builtin_amdgcn_mfma_f32_16x16x32_bf16(w, xf[0], acc[0][tt], 0, 0, 0);
                acc[1][tt] = __builtin_amdgcn_mfma_f32_16x16x32_bf16(w, xf[1], acc[1][tt], 0, 0, 0);
            }
        }
#pragma unroll
        for (int nt = 0; nt < 2; nt++) {
            int nd = nt ? nodeB : nodeA;
            if (nd >= N_NODES) continue;
#pragma unroll
            for (int tt = 0; tt < 8; tt++) {
                uint2 o;
                o.x = (unsigned int)bf16rne(acc[nt][tt][0]) |
                      ((unsigned int)bf16rne(acc[nt][tt][1]) << 16);
                o.y = (unsigned int)bf16rne(acc[nt][tt][2]) |
                      ((unsigned int)bf16rne(acc[nt][tt][3]) << 16);
                *(uint2*)&Yb[(size_t)nd * 128 + tt * 16 + quad * 4] = o;
            }
        }
        return;
    }

    // ---- binA (r8-proven) ----
    uint2* recs = (uint2*)big;              // 32 KB
    int*   gdst = (int*)(big + 32768);      // 16 KB
    for (int i = t; i < NB; i += 256) { hcnt[i] = 0; hofs[i] = 0; }
    __syncthreads();

    const int e0 = blockIdx.x * EPB;
    int cc[16], rr[16]; float ee[16];
#pragma unroll
    for (int i = 0; i < 16; i++) {
        int e = e0 + i * 256 + t;
        if (e < NE) { cc[i] = col[e]; rr[i] = row[e]; ee[i] = ew[e]; }
        else cc[i] = -1;
    }
#pragma unroll
    for (int i = 0; i < 16; i++)
        if (cc[i] >= 0) atomicAdd(&hcnt[cc[i] >> 10], 1);
    __syncthreads();
    if (t < NB) {
        int c = hcnt[t];
        hbase[t] = c ? atomicAdd(&gbcur[t * GSTRIDE], c) : 0;
    }
    if (t < 128) scn[t] = (t < NB) ? hcnt[t] : 0;
    __syncthreads();
    for (int off = 1; off < 128; off <<= 1) {
        int v = 0;
        if (t < 128 && t >= off) v = scn[t - off];
        __syncthreads();
        if (t < 128) scn[t] += v;
        __syncthreads();
    }
    if (t < NB) lofs[t] = scn[t] - hcnt[t];
    __syncthreads();
#pragma unroll
    for (int i = 0; i < 16; i++) {
        if (cc[i] < 0) continue;
        int b = cc[i] >> 10;
        int lpos = atomicAdd(&hofs[b], 1);
        int si = lofs[b] + lpos;
        unsigned int meta = ((unsigned int)(cc[i] & 1023) << 17) | (unsigned int)rr[i];
        recs[si] = make_uint2(meta, __float_as_uint(ee[i]));
        int gp = hbase[b] + lpos;
        gdst[si] = (gp < BCAP) ? (b * BCAP + gp) : -1;
    }
    __syncthreads();
    const int valid = lofs[NB - 1] + hcnt[NB - 1];
    for (int i = t; i < valid; i += 256) {
        int g = gdst[i];
        if (g >= 0) babuf[g] = recs[i];
    }
}

// ---- binB: single-pass per-bucket build (r8-proven) -----------------------
__global__ __launch_bounds__(1024) void binB_kernel(const int* __restrict__ gbcur,
                                                    const uint2* __restrict__ babuf,
                                                    float* __restrict__ dinv,
                                                    uint2* __restrict__ cursor2,
                                                    uint2* __restrict__ sedge) {
    __shared__ unsigned long long pk[1024];   // 8 KB
    __shared__ int ofs[1024];
    __shared__ int wtot[16];
    const int b = blockIdx.x, t = threadIdx.x;
    const int n0 = b << 10;
    const int nn = min(1024, N_NODES - n0);

    pk[t] = 0ull;
    __syncthreads();

    const int msize = min(gbcur[b * GSTRIDE], BCAP);
    const int nslots = (msize + 1023) >> 10;
    const uint2* bb = babuf + (size_t)b * BCAP;
    uint2 rec[20];
#pragma unroll
    for (int slot = 0; slot < 20; slot++) {
        int i = (slot << 10) + t;
        bool v = (slot < nslots) && (i < msize);
        uint2 m = v ? bb[i] : make_uint2(0u, 0u);
        rec[slot] = m;
        if (v) {
            unsigned long long add = (1ull << 44) +
                (unsigned long long)(__uint_as_float(m.y) * 4294967296.0f);
            atomicAdd(&pk[m.x >> 17], add);
        }
    }
    __syncthreads();

    const unsigned long long p = pk[t];
    const int myc = (int)(p >> 44);
    const float deg = (float)(p & ((1ull << 44) - 1)) * (1.0f / 4294967296.0f);
    if (t < nn) dinv[n0 + t] = 1.0f / sqrtf(deg + 1.0f);

    const int lane64 = t & 63, w = t >> 6;
    int s = myc;
#pragma unroll
    for (int off = 1; off < 64; off <<= 1) {
        int u = __shfl_up(s, off);
        if (lane64 >= off) s += u;
    }
    if (lane64 == 63) wtot[w] = s;
    __syncthreads();
    if (t < 16) {
        int u = wtot[t];
#pragma unroll
        for (int off = 1; off < 16; off <<= 1) {
            int uu = __shfl_up(u, off);
            if (t >= off) u += uu;
        }
        wtot[t] = u;
    }
    __syncthreads();
    const int excl = s + (w ? wtot[w - 1] : 0) - myc;
    ofs[t] = excl;

    const unsigned int ebase = (unsigned int)b * BCAP;
    if (t < nn) {
        unsigned int st = ebase + (unsigned int)excl;
        cursor2[n0 + t] = make_uint2(st, st + (unsigned int)myc);
    }
    __syncthreads();

#pragma unroll
    for (int slot = 0; slot < 20; slot++) {
        int i = (slot << 10) + t;
        bool v = (slot < nslots) && (i < msize);
        if (v) {
            uint2 m = rec[slot];
            int cl = m.x >> 17;
            int pp = atomicAdd(&ofs[cl], 1);
            sedge[(size_t)b * BCAP + pp] = make_uint2(m.x & 0x1FFFFu, m.y);
        }
    }
}

// ---- FUSED gather + next-layer GEMM: 32 nodes/block, 512 threads ----------
// xin/xout UNSCALED; per-edge w = ew*dinv[r]. W fragments for the MFMA phase
// are PREFETCHED into registers before the gather loop (independent of the
// gather; their L2 latency hides under the ~60us gather phase), so the
// post-barrier path is pure LDS-read -> MFMA.
__global__ __launch_bounds__(512) void fused_gg(const uint2* __restrict__ cursor2,
                                                const uint2* __restrict__ sedge,
                                                const unsigned short* __restrict__ xin,
                                                const float* __restrict__ dinv,
                                                const float* __restrict__ bias,
                                                const unsigned short* __restrict__ Wt,
                                                unsigned short* __restrict__ xout) {
    __shared__ unsigned short sH[32 * 168];    // 10752 B
    const int tid = threadIdx.x;

    const int ln   = tid >> 4;              // local node 0..31 (gather role)
    const int node = blockIdx.x * 32 + ln;  // grid exact
    const int lane = tid & 15;
    const int wave = tid >> 6;              // MFMA role
    const int l64  = tid & 63;
    const int m    = l64 & 15, quad = l64 >> 4;

    // prefetch this wave's 4 W fragments (16 VGPRs, live across gather)
    short8 wf[4];
#pragma unroll
    for (int kc = 0; kc < 4; kc++)
        wf[kc] = *(const short8*)&Wt[(size_t)(wave * 16 + m) * 128 + kc * 32 + quad * 8];

    uint2 cu = cursor2[node];
    int e = (int)cu.x, end = (int)cu.y;
    const uint4* tab = (const uint4*)xin;

    const float dv = dinv[node];
    uint4 q0 = tab[(size_t)node * 16 + lane];
    float4 aL, aH;
    aL.x = dv * blo(q0.x); aL.y = dv * bhi(q0.x);
    aL.z = dv * blo(q0.y); aL.w = dv * bhi(q0.y);
    aH.x = dv * blo(q0.z); aH.y = dv * bhi(q0.z);
    aH.z = dv * blo(q0.w); aH.w = dv * bhi(q0.w);

    for (; e + 4 <= end; e += 4) {
        uint2 E[4]; uint4 q[4]; float dr[4];
#pragma unroll
        for (int j = 0; j < 4; j++) E[j] = sedge[e + j];
#pragma unroll
        for (int j = 0; j < 4; j++) { q[j] = tab[(size_t)E[j].x * 16 + lane]; dr[j] = dinv[E[j].x]; }
#pragma unroll
        for (int j = 0; j < 4; j++) {
            float w = __uint_as_float(E[j].y) * dr[j];
            aL.x += w * blo(q[j].x); aL.y += w * bhi(q[j].x);
            aL.z += w * blo(q[j].y); aL.w += w * bhi(q[j].y);
            aH.x += w * blo(q[j].z); aH.y += w * bhi(q[j].z);
            aH.z += w * blo(q[j].w); aH.w += w * bhi(q[j].w);
        }
    }
    for (; e < end; ++e) {
        uint2 E = sedge[e];
        float w = __uint_as_float(E.y) * dinv[E.x];
        uint4 q = tab[(size_t)E.x * 16 + lane];
        aL.x += w * blo(q.x); aL.y += w * bhi(q.x);
        aL.z += w * blo(q.y); aL.w += w * bhi(q.y);
        aH.x += w * blo(q.z); aH.y += w * bhi(q.z);
        aH.z += w * blo(q.w); aH.w += w * bhi(q.w);
    }

    {
        float4 b0 = ((const float4*)bias)[lane * 2];
        float4 b1 = ((const float4*)bias)[lane * 2 + 1];
        aL.x = fmaxf(fmaf(dv, aL.x, b0.x), 0.f);
        aL.y = fmaxf(fmaf(dv, aL.y, b0.y), 0.f);
        aL.z = fmaxf(fmaf(dv, aL.z, b0.z), 0.f);
        aL.w = fmaxf(fmaf(dv, aL.w, b0.w), 0.f);
        aH.x = fmaxf(fmaf(dv, aH.x, b1.x), 0.f);
        aH.y = fmaxf(fmaf(dv, aH.y, b1.y), 0.f);
        aH.z = fmaxf(fmaf(dv, aH.z, b1.z), 0.f);
        aH.w = fmaxf(fmaf(dv, aH.w, b1.w), 0.f);
        uint4 o;
        o.x = (unsigned int)bf16rne(aL.x) | ((unsigned int)bf16rne(aL.y) << 16);
        o.y = (unsigned int)bf16rne(aL.z) | ((unsigned int)bf16rne(aL.w) << 16);
        o.z = (unsigned int)bf16rne(aH.x) | ((unsigned int)bf16rne(aH.y) << 16);
        o.w = (unsigned int)bf16rne(aH.z) | ((unsigned int)bf16rne(aH.w) << 16);
        *(uint4*)&sH[ln * 168 + lane * 8] = o;
    }
    __syncthreads();

    // ---- MFMA phase: wave w covers outcols w*16..+15, all 32 nodes ----
    float4v acc0 = (float4v){0.f, 0.f, 0.f, 0.f};
    float4v acc1 = (float4v){0.f, 0.f, 0.f, 0.f};

#pragma unroll
    for (int kc = 0; kc < 4; kc++) {
        const int k0 = kc * 32 + quad * 8;
        short8 h0 = *(const short8*)&sH[m * 168 + k0];
        short8 h1 = *(const short8*)&sH[(16 + m) * 168 + k0];
        acc0 = __builtin_amdgcn_mfma_f32_16x16x32_bf16(wf[kc], h0, acc0, 0, 0, 0);
        acc1 = __builtin_amdgcn_mfma_f32_16x16x32_bf16(wf[kc], h1, acc1, 0, 0, 0);
    }

#pragma unroll
    for (int nt = 0; nt < 2; nt++) {
        int nd = blockIdx.x * 32 + nt * 16 + m;
        float4v a = nt ? acc1 : acc0;
        uint2 o;
        o.x = (unsigned int)bf16rne(a[0]) | ((unsigned int)bf16rne(a[1]) << 16);
        o.y = (unsigned int)bf16rne(a[2]) | ((unsigned int)bf16rne(a[3]) << 16);
        *(uint2*)&xout[(size_t)nd * 128 + wave * 16 + quad * 4] = o;
    }
}

// -------- CSR gather (final layer): fused linear output --------------------
__global__ __launch_bounds__(256) void gather_csr(const uint2* __restrict__ cursor2,
                                                  const uint2* __restrict__ sedge,
                                                  const unsigned short* __restrict__ xwb,
                                                  const float* __restrict__ dinv,
                                                  const float* __restrict__ bias,
                                                  float* __restrict__ outp,
                                                  const float* __restrict__ lw,
                                                  const float* __restrict__ lb) {
    int node = blockIdx.x * 16 + (threadIdx.x >> 4);
    int lane = threadIdx.x & 15;
    if (node >= N_NODES) return;
    uint2 cu = cursor2[node];
    int e = (int)cu.x, end = (int)cu.y;
    const uint4* tab = (const uint4*)xwb;

    const float dv = dinv[node];
    uint4 q0 = tab[(size_t)node * 16 + lane];
    float4 aL, aH;
    aL.x = dv * blo(q0.x); aL.y = dv * bhi(q0.x);
    aL.z = dv * blo(q0.y); aL.w = dv * bhi(q0.y);
    aH.x = dv * blo(q0.z); aH.y = dv * bhi(q0.z);
    aH.z = dv * blo(q0.w); aH.w = dv * bhi(q0.w);

    for (; e + 4 <= end; e += 4) {
        uint2 E[4]; uint4 q[4]; float dr[4];
#pragma unroll
        for (int j = 0; j < 4; j++) E[j] = sedge[e + j];
#pragma unroll
        for (int j = 0; j < 4; j++) { q[j] = tab[(size_t)E[j].x * 16 + lane]; dr[j] = dinv[E[j].x]; }
#pragma unroll
        for (int j = 0; j < 4; j++) {
            float w = __uint_as_float(E[j].y) * dr[j];
            aL.x += w * blo(q[j].x); aL.y += w * bhi(q[j].x);
            aL.z += w * blo(q[j].y); aL.w += w * bhi(q[j].y);
            aH.x += w * blo(q[j].z); aH.y += w * bhi(q[j].z);
            aH.z += w * blo(q[j].w); aH.w += w * bhi(q[j].w);
        }
    }
    for (; e < end; ++e) {
        uint2 E = sedge[e];
        float w = __uint_as_float(E.y) * dinv[E.x];
        uint4 q = tab[(size_t)E.x * 16 + lane];
        aL.x += w * blo(q.x); aL.y += w * bhi(q.x);
        aL.z += w * blo(q.y); aL.w += w * bhi(q.y);
        aH.x += w * blo(q.z); aH.y += w * bhi(q.z);
        aH.z += w * blo(q.w); aH.w += w * bhi(q.w);
    }

    float4 b0 = ((const float4*)bias)[lane * 2];
    float4 b1 = ((const float4*)bias)[lane * 2 + 1];
    aL.x = fmaxf(fmaf(dv, aL.x, b0.x), 0.f);
    aL.y = fmaxf(fmaf(dv, aL.y, b0.y), 0.f);
    aL.z = fmaxf(fmaf(dv, aL.z, b0.z), 0.f);
    aL.w = fmaxf(fmaf(dv, aL.w, b0.w), 0.f);
    aH.x = fmaxf(fmaf(dv, aH.x, b1.x), 0.f);
    aH.y = fmaxf(fmaf(dv, aH.y, b1.y), 0.f);
    aH.z = fmaxf(fmaf(dv, aH.z, b1.z), 0.f);
    aH.w = fmaxf(fmaf(dv, aH.w, b1.w), 0.f);

    float4 w0 = ((const float4*)lw)[lane * 2];
    float4 w1 = ((const float4*)lw)[lane * 2 + 1];
    float p = aL.x * w0.x + aL.y * w0.y + aL.z * w0.z + aL.w * w0.w +
              aH.x * w1.x + aH.y * w1.y + aH.z * w1.z + aH.w * w1.w;
#pragma unroll
    for (int off = 8; off; off >>= 1) p += __shfl_down(p, off);
    if (lane == 0) outp[node] = p + lb[0];
}

extern "C" void kernel_launch(void* const* d_in, const int* in_sizes, int n_in,
                              void* d_out, int out_size, void* d_ws, size_t ws_size,
                              hipStream_t stream) {
    const float* x   = (const float*)d_in[0];
    const int*   ei  = (const int*)d_in[1];   // int64 in reference -> int32 on device
    const float* ea  = (const float*)d_in[2];
    const float* W1  = (const float*)d_in[3];
    const float* b1  = (const float*)d_in[4];
    const float* W2  = (const float*)d_in[5];
    const float* b2  = (const float*)d_in[6];
    const float* W3  = (const float*)d_in[7];
    const float* b3  = (const float*)d_in[8];
    const float* lw  = (const float*)d_in[9];
    const float* lb  = (const float*)d_in[10];
    float*       out = (float*)d_out;

    const int* row = ei;        // edge_index[0]
    const int* col = ei + NE;   // edge_index[1]

    const int BS = 256;
    int gGather = (N_NODES + 15) / 16;    // 6250
    int gFused  = N_NODES / 32;           // 3125, exact
    int gCombo  = NBLKA + 1 + GEMMB;      // 391 binA + 1 wt3 + 782 gemm

    // workspace layout (~84 MB):
    //   babuf uint2[NB*BCAP] | sedge uint2[NB*BCAP] | cursor2 uint2[N] |
    //   dinv f[N] | gbcur i[128*GSTRIDE] | Wt u16[3*16384] | xwbA | xwbB
    char* wsb = (char*)d_ws;
    uint2*          babuf   = (uint2*)wsb;          wsb += (size_t)NB * BCAP * 8;
    uint2*          sedge   = (uint2*)wsb;          wsb += (size_t)NB * BCAP * 8;
    uint2*          cursor2 = (uint2*)wsb;          wsb += (size_t)N_NODES * 8;
    float*          dinv    = (float*)wsb;          wsb += (size_t)N_NODES * 4;
    int*            gbcur   = (int*)wsb;            wsb += 128 * GSTRIDE * 4;
    unsigned short* Wt      = (unsigned short*)wsb; wsb += 3 * 16384 * 2;
    unsigned short* xwbA    = (unsigned short*)wsb; wsb += (size_t)N_NODES * C * 2;
    unsigned short* xwbB    = (unsigned short*)wsb;

    hipMemsetAsync(gbcur, 0, 128 * GSTRIDE * 4, stream);
    // combined: binA buckets + wt3 + layer-1 gemm (gemm is dinv-independent)
    binA_kernel<<<gCombo, BS, 0, stream>>>(row, col, ea, gbcur, babuf,
                                           W1, W2, W3, Wt, x, xwbA);
    binB_kernel<<<NB, 1024, 0, stream>>>(gbcur, babuf, dinv, cursor2, sedge);

    // layer 1 gather + layer 2 projection (fused): -> xwbB
    fused_gg<<<gFused, 512, 0, stream>>>(cursor2, sedge, xwbA, dinv, b1,
                                         Wt + 16384, xwbB);
    // layer 2 gather + layer 3 projection (fused): -> xwbA
    fused_gg<<<gFused, 512, 0, stream>>>(cursor2, sedge, xwbB, dinv, b2,
                                         Wt + 32768, xwbA);
    // layer 3 gather + final linear
    gather_csr<<<gGather, BS, 0, stream>>>(cursor2, sedge, xwbA, dinv, b3,
                                           out, lw, lb);
}